// Round 5
// baseline (209.510 us; speedup 1.0000x reference)
//
#include <hip/hip_runtime.h>
#include <hip/hip_bf16.h>
#include <math.h>

#define NH   16
#define NKV  4
#define HD   64
#define B_   2
#define T_   2048
#define C_   1024
#define QKVN 1536   // fused q(1024) | k(256) | v(256)

typedef __attribute__((ext_vector_type(8))) short short8;
typedef __attribute__((ext_vector_type(4))) float v4f;

__device__ inline ushort f2bf(float f) {
    union { float f; uint32_t u; } v; v.f = f;
    uint32_t r = v.u + 0x7fffu + ((v.u >> 16) & 1u);
    return (ushort)(r >> 16);
}

// pack two f32 -> one dword of bf16
__device__ inline uint pk_bf16(float a, float b) {
#if __has_builtin(__builtin_amdgcn_cvt_pk_bf16_f32)
    auto v = __builtin_amdgcn_cvt_pk_bf16_f32(a, b);
    union { decltype(v) v2; uint u; } cv; cv.v2 = v; return cv.u;
#else
    return (uint)f2bf(a) | ((uint)f2bf(b) << 16);
#endif
}

__device__ inline float ex2(float x) {
#if __has_builtin(__builtin_amdgcn_exp2f)
    return __builtin_amdgcn_exp2f(x);
#else
    return exp2f(x);
#endif
}

// async global->LDS, 16B per lane; LDS dest wave-uniform base + lane*16
__device__ inline void async16(const void* g, void* l) {
    __builtin_amdgcn_global_load_lds(
        (const __attribute__((address_space(1))) unsigned int*)g,
        (__attribute__((address_space(3))) unsigned int*)l, 16, 0, 0);
}

// ---------------- prep: x f32->bf16 convert + 4 weight transposes ----------
__global__ __launch_bounds__(256) void prep(
    const float* __restrict__ x,
    const float* __restrict__ Wq, const float* __restrict__ Wk,
    const float* __restrict__ Wv, const float* __restrict__ Wo,
    ushort* __restrict__ xb, ushort* __restrict__ WqkvT, ushort* __restrict__ WoT)
{
    const int bx = blockIdx.x;
    const int tid = threadIdx.x;
    if (bx < 640) {
        __shared__ float tile[64][65];
        const int cb = bx >> 4;
        const int kb = bx & 15;
        const float* src; ushort* dst; int N, nb;
        if (cb < 16)      { src = Wq; dst = WqkvT;                     N = 1024; nb = cb; }
        else if (cb < 20) { src = Wk; dst = WqkvT + (size_t)1024 * C_; N = 256;  nb = cb - 16; }
        else if (cb < 24) { src = Wv; dst = WqkvT + (size_t)1280 * C_; N = 256;  nb = cb - 20; }
        else              { src = Wo; dst = WoT;                       N = 1024; nb = cb - 24; }
        const int k0 = kb * 64, n0 = nb * 64;
        #pragma unroll
        for (int it = 0; it < 4; ++it) {
            int r = (tid >> 4) + it * 16;
            int c = (tid & 15) * 4;
            float4 v = *(const float4*)(src + (size_t)(k0 + r) * N + n0 + c);
            tile[r][c] = v.x; tile[r][c + 1] = v.y; tile[r][c + 2] = v.z; tile[r][c + 3] = v.w;
        }
        __syncthreads();
        #pragma unroll
        for (int it = 0; it < 4; ++it) {
            int r = (tid >> 4) + it * 16;
            int c = (tid & 15) * 4;
            ushort4 o;
            o.x = f2bf(tile[c + 0][r]); o.y = f2bf(tile[c + 1][r]);
            o.z = f2bf(tile[c + 2][r]); o.w = f2bf(tile[c + 3][r]);
            *(ushort4*)(dst + (size_t)(n0 + r) * C_ + k0 + c) = o;
        }
    } else {
        int i = ((bx - 640) * 256 + tid) * 4;   // covers 4096*1024 exactly
        float4 v = *(const float4*)(x + i);
        ushort4 o; o.x = f2bf(v.x); o.y = f2bf(v.y); o.z = f2bf(v.z); o.w = f2bf(v.w);
        *(ushort4*)(xb + i) = o;
    }
}

// ---------------- bf16 MFMA GEMM: C[M,N] = A[M,K] @ Bt[N,K]^T --------------
// 128(M)x64(N) tile, BK=32, 4 waves stacked along M (wave: 32m x 64n),
// double-buffered LDS, ONE raw barrier per iter, async global_load_lds
// prefetch in flight across the whole compute of iter i. (Proven config;
// 128x128 widening regressed ~7us from grid granularity.)
// ROPE path (QKV gemm): n0<1024 -> rope + 0.125*log2e scale (exp2 softmax);
// 1024..1279 -> rope only (k); n0>=1280 -> v stored transposed into vT.
template <bool BF16OUT, bool ROPE>
__global__ __launch_bounds__(256) void gemm_bf16bt(
    const ushort* __restrict__ A, const ushort* __restrict__ Bt,
    void* __restrict__ Cout, ushort* __restrict__ vTout,
    const float* __restrict__ cs, const float* __restrict__ sn,
    int M, int N, int K)
{
    __shared__ __align__(16) short As[2][128 * 32];
    __shared__ __align__(16) short Bs[2][64 * 32];

    const int tid  = threadIdx.x;
    const int lane = tid & 63;
    const int wid  = tid >> 6;
    const int l16  = lane & 15;
    const int quad = lane >> 4;
    const int m0   = blockIdx.y * 128;
    const int n0   = blockIdx.x * 64;

    const ushort* agb = A  + (size_t)(m0 + wid * 32 + (lane >> 2)) * K + (lane & 3) * 8;
    const ushort* bgb = Bt + (size_t)(n0 + wid * 16 + (lane >> 2)) * K + (lane & 3) * 8;

    v4f acc[2][4];
    #pragma unroll
    for (int i = 0; i < 2; ++i)
        #pragma unroll
        for (int j = 0; j < 4; ++j) acc[i][j] = (v4f){0.f, 0.f, 0.f, 0.f};

    // prologue: stage iter 0 into buf 0
    async16(agb,                  &As[0][(wid * 32) * 32]);
    async16(agb + (size_t)16 * K, &As[0][(wid * 32 + 16) * 32]);
    async16(bgb,                  &Bs[0][(wid * 16) * 32]);

    const int nIter = K >> 5;
    for (int it = 0; it < nIter; ++it) {
        // drain own buf-it DMA (only thing in flight), publish to block.
        asm volatile("s_waitcnt vmcnt(0)\n\ts_barrier" ::: "memory");

        // prefetch iter it+1 into the other buffer; in flight across compute.
        if (it + 1 < nIter) {
            const int nb = (it + 1) & 1;
            const int k0 = (it + 1) << 5;
            async16(agb + k0,                  &As[nb][(wid * 32) * 32]);
            async16(agb + k0 + (size_t)16 * K, &As[nb][(wid * 32 + 16) * 32]);
            async16(bgb + k0,                  &Bs[nb][(wid * 16) * 32]);
        }

        const short* Ab = As[it & 1];
        const short* Bb = Bs[it & 1];
        short8 af[2], bf[4];
        #pragma unroll
        for (int i = 0; i < 2; ++i)
            af[i] = *(const short8*)&Ab[(wid * 32 + i * 16 + l16) * 32 + quad * 8];
        #pragma unroll
        for (int j = 0; j < 4; ++j)
            bf[j] = *(const short8*)&Bb[(j * 16 + l16) * 32 + quad * 8];
        #pragma unroll
        for (int i = 0; i < 2; ++i)
            #pragma unroll
            for (int j = 0; j < 4; ++j)
                acc[i][j] = __builtin_amdgcn_mfma_f32_16x16x32_bf16(af[i], bf[j], acc[i][j], 0, 0, 0);
    }

    if (ROPE && n0 >= 1280) {
        // v tile: store transposed to vT[(b*256 + (col-1280))][t]
        #pragma unroll
        for (int i = 0; i < 2; ++i) {
            const int row = m0 + wid * 32 + i * 16 + quad * 4;   // 4 consecutive t
            const int bb  = row >> 11;
            const int t   = row & (T_ - 1);
            #pragma unroll
            for (int j = 0; j < 4; ++j) {
                const int vc = n0 - 1280 + j * 16 + l16;
                ushort4 o;
                o.x = f2bf(acc[i][j][0]); o.y = f2bf(acc[i][j][1]);
                o.z = f2bf(acc[i][j][2]); o.w = f2bf(acc[i][j][3]);
                *(ushort4*)(vTout + (size_t)(bb * 256 + vc) * T_ + t) = o;
            }
        }
        return;
    }

    if (ROPE) {
        // q gets 0.125 * log2(e) so attention works in exp2 domain
        const float qs = (n0 < 1024) ? 0.18033688f : 1.0f;
        #pragma unroll
        for (int i = 0; i < 2; ++i) {
            #pragma unroll
            for (int r = 0; r < 4; ++r) {
                const int row = m0 + wid * 32 + i * 16 + quad * 4 + r;
                const int t = row & (T_ - 1);
                #pragma unroll
                for (int j = 0; j < 2; ++j) {
                    const int d = j * 16 + l16;
                    float cv = cs[t * 32 + d] * qs, sv = sn[t * 32 + d] * qs;
                    float x1 = acc[i][j][r], x2 = acc[i][j + 2][r];
                    acc[i][j][r]     = x1 * cv - x2 * sv;
                    acc[i][j + 2][r] = x2 * cv + x1 * sv;
                }
            }
        }
    }

    #pragma unroll
    for (int i = 0; i < 2; ++i) {
        #pragma unroll
        for (int r = 0; r < 4; ++r) {
            const int row = m0 + wid * 32 + i * 16 + quad * 4 + r;
            #pragma unroll
            for (int j = 0; j < 4; ++j) {
                const int col = n0 + j * 16 + l16;
                if (BF16OUT)
                    ((ushort*)Cout)[(size_t)row * N + col] = f2bf(acc[i][j][r]);
                else
                    ((float*)Cout)[(size_t)row * N + col] = acc[i][j][r];
            }
        }
    }
}

// ---------------- MFMA flash attention: 128-key chunks -------------------
// R16 = R15 + a REAL issue-point pin for the V register staging.
// R4's counters (VGPR_Count=84) proved the compiler sank the 16 V loads to
// just before PV (legal: the lgkmcnt asm only upper-bounds placement),
// re-exposing the L2 latency (MfmaUtil 8.6, dur 83us). Fix per rule #18:
// sched_barrier(0) + memory-clobber asm IMMEDIATELY after the staging
// block — loads cannot sink across, K-prefetch/QK cannot hoist above.
// Expected VGPR ~145 (vv held live), pre-PV wait = vmcnt(4) on loads
// issued ~2000cy earlier (covered by QK^T + softmax).
// Keeps: no Vs in LDS -> 50.2KB -> 3 blocks/CU; ONE barrier per chunk;
// grid 1024 single-tile blocks, heavy tiles first, XCD swizzle.
#define PSTR 136
__global__ __launch_bounds__(256, 3) void attn_mfma(
    const ushort* __restrict__ qkv, const ushort* __restrict__ vT,
    ushort* __restrict__ y)
{
    __shared__ __align__(16) short Ks[2][128 * 64];   // [key][d] 128B rows
    __shared__ __align__(16) short Ps[4][16][PSTR];

    const int tid  = threadIdx.x;
    const int wid  = tid >> 6;
    const int ln   = tid & 63;
    const int l16  = ln & 15;
    const int quad = ln >> 4;

    const int bi   = blockIdx.x;          // 0..1023
    const int xcd  = bi & 7;
    const int b    = xcd >> 2;
    const int kvh  = xcd & 3;
    const int jj   = bi >> 3;             // 0..127
    const int h    = kvh * 4 + (jj & 3);
    const int tb   = 31 - (jj >> 2);      // heavy tiles first

    const ushort* kbase = qkv + (size_t)(b * T_) * QKVN + 1024 + kvh * HD;
    const ushort* vtb   = vT + (size_t)(b * 256 + kvh * HD) * T_;

    // K staging: wave stages rows r0..r0+31 (128B rows, 8 x16B blocks/row)
    const int r0   = wid * 32;
    const int srow = ln >> 3;                     // 0..7
    const int sblk = ((ln & 7) ^ srow) * 8;       // XOR-swizzled source col
    const int sl0  = (quad ^ (l16 & 7)) * 8;      // K frag slot, d-blocks 0..3
    const int sl1  = sl0 ^ 32;                    // d-blocks 4..7

    const int q0  = tb * 64;
    const int nch = tb / 2 + 1;               // 128-key chunks

    // Q B-fragments (pre-scaled by 0.125*log2e): B[n=l16][k=quad*8+j]
    short8 qf0, qf1;
    {
        const ushort* qrow = qkv + (size_t)(b * T_ + q0 + wid * 16 + l16) * QKVN + h * HD;
        qf0 = *(const short8*)(qrow + quad * 8);
        qf1 = *(const short8*)(qrow + 32 + quad * 8);
    }

    v4f oacc[4];
    #pragma unroll
    for (int t = 0; t < 4; ++t) oacc[t] = (v4f){0.f, 0.f, 0.f, 0.f};
    float m = -1e30f, l = 0.f;   // l: per-lane PARTIAL (this quad's keys)

    // prologue: stage K chunk 0 (128 rows) into buf 0
    {
        const ushort* kg = kbase + (size_t)(r0 + srow) * QKVN + sblk;
        async16(kg,                     &Ks[0][(r0     ) * 64]);
        async16(kg + (size_t) 8 * QKVN, &Ks[0][(r0 +  8) * 64]);
        async16(kg + (size_t)16 * QKVN, &Ks[0][(r0 + 16) * 64]);
        async16(kg + (size_t)24 * QKVN, &Ks[0][(r0 + 24) * 64]);
    }

    for (int c = 0; c < nch; ++c) {
        const int key0 = c * 128;
        // ONE barrier per chunk: compiler vmcnt(0) drains own K chunk-c DMA,
        // s_barrier publishes to block.
        __syncthreads();

        // ---- stage V chunk c -> REGISTERS, issued HERE (chunk top).
        // vv[t][seg] = vT[d = t*16+l16][key0 + seg*32 + quad*8 .. +8] —
        // byte-identical to what the old LDS staging delivered.
        short8 vv[4][4];
        {
            const ushort* vrow = vtb + (size_t)l16 * T_ + key0 + quad * 8;
            #pragma unroll
            for (int t = 0; t < 4; ++t) {
                const ushort* vr = vrow + (size_t)(t * 16) * T_;
                #pragma unroll
                for (int seg = 0; seg < 4; ++seg)
                    vv[t][seg] = *(const short8*)(vr + seg * 32);
            }
        }
        // PIN (rule #18): loads above may NOT sink past this point; the
        // K-prefetch / QK below may not hoist above it. This is what R4
        // was missing — the compiler sank all 16 loads to just before PV.
        __builtin_amdgcn_sched_barrier(0);
        asm volatile("" ::: "memory");

        // prefetch K chunk c+1; in flight across this whole chunk's compute
        if (c + 1 < nch) {
            const int nb = (c + 1) & 1;
            const ushort* kg = kbase + (size_t)(key0 + 128 + r0 + srow) * QKVN + sblk;
            async16(kg,                     &Ks[nb][(r0     ) * 64]);
            async16(kg + (size_t) 8 * QKVN, &Ks[nb][(r0 +  8) * 64]);
            async16(kg + (size_t)16 * QKVN, &Ks[nb][(r0 + 16) * 64]);
            async16(kg + (size_t)24 * QKVN, &Ks[nb][(r0 + 24) * 64]);
        }
        const short* Kb = Ks[c & 1];

        // ---- S^T = K @ Q^T (row=key, col=query), 8 key-tiles ----
        v4f st[8];
        __builtin_amdgcn_s_setprio(1);
        #pragma unroll
        for (int t = 0; t < 8; ++t) {
            short8 k0f = *(const short8*)&Kb[(t * 16 + l16) * 64 + sl0];
            short8 k1f = *(const short8*)&Kb[(t * 16 + l16) * 64 + sl1];
            v4f s = (v4f){0.f, 0.f, 0.f, 0.f};
            s = __builtin_amdgcn_mfma_f32_16x16x32_bf16(k0f, qf0, s, 0, 0, 0);
            s = __builtin_amdgcn_mfma_f32_16x16x32_bf16(k1f, qf1, s, 0, 0, 0);
            st[t] = s;
        }
        __builtin_amdgcn_s_setprio(0);

        // causal mask: only the chunk containing the diagonal
        if (c == nch - 1) {
            const int qg = wid * 16 + l16 + q0;
            #pragma unroll
            for (int t = 0; t < 8; ++t)
                #pragma unroll
                for (int r = 0; r < 4; ++r)
                    if (key0 + t * 16 + quad * 4 + r > qg) st[t][r] = -1e30f;
        }

        // ---- online softmax (exp2 domain), tree-reduced, defer-max ----
        float tm[8];
        #pragma unroll
        for (int t = 0; t < 8; ++t)
            tm[t] = fmaxf(fmaxf(st[t][0], st[t][1]), fmaxf(st[t][2], st[t][3]));
        float mx = fmaxf(fmaxf(fmaxf(tm[0], tm[1]), fmaxf(tm[2], tm[3])),
                         fmaxf(fmaxf(tm[4], tm[5]), fmaxf(tm[6], tm[7])));
        // common path: max grew by <= 8 for every lane -> keep old m,
        // skip cross-quad shfls and the whole rescale pass.
        if (!__all(mx <= m + 8.0f)) {
            float mf = fmaxf(mx, __shfl_xor(mx, 16, 64));
            mf = fmaxf(mf, __shfl_xor(mf, 32, 64));
            const float mnew  = fmaxf(m, mf);
            const float alpha = ex2(m - mnew);
            m = mnew;
            l *= alpha;
            #pragma unroll
            for (int t = 0; t < 4; ++t)
                #pragma unroll
                for (int r = 0; r < 4; ++r) oacc[t][r] *= alpha;
        }
        // p overwrites st in-place (keeps register pressure down)
        float ts[8];
        #pragma unroll
        for (int t = 0; t < 8; ++t) {
            st[t][0] = ex2(st[t][0] - m); st[t][1] = ex2(st[t][1] - m);
            st[t][2] = ex2(st[t][2] - m); st[t][3] = ex2(st[t][3] - m);
            ts[t] = (st[t][0] + st[t][1]) + (st[t][2] + st[t][3]);
        }
        l += ((ts[0] + ts[1]) + (ts[2] + ts[3])) +
             ((ts[4] + ts[5]) + (ts[6] + ts[7]));

        // write P^T rows: Ps[query=l16][key], packed pairs -> b64
        #pragma unroll
        for (int t = 0; t < 8; ++t) {
            uint2 w;
            w.x = pk_bf16(st[t][0], st[t][1]);
            w.y = pk_bf16(st[t][2], st[t][3]);
            *(uint2*)&Ps[wid][l16][t * 16 + quad * 4] = w;
        }

        // drain this wave's P ds_writes, read own P fragments (per-wave
        // scratch -> no barrier needed)
        asm volatile("s_waitcnt lgkmcnt(0)" ::: "memory");
        short8 pa[4];
        #pragma unroll
        for (int seg = 0; seg < 4; ++seg)
            pa[seg] = *(const short8*)&Ps[wid][l16][seg * 32 + quad * 8];

        // ---- O^T += V^T @ P^T : V from registers (staged at chunk top;
        // compiler waits vmcnt(4) here — K-prefetch stays in flight) ----
        __builtin_amdgcn_s_setprio(1);
        #pragma unroll
        for (int t = 0; t < 4; ++t)
            #pragma unroll
            for (int seg = 0; seg < 4; ++seg)
                oacc[t] = __builtin_amdgcn_mfma_f32_16x16x32_bf16(vv[t][seg], pa[seg], oacc[t], 0, 0, 0);
        __builtin_amdgcn_s_setprio(0);
    }

    // epilogue: cross-quad reduce the partial l, then y = O^T / l
    float lt = l + __shfl_xor(l, 16, 64);
    lt += __shfl_xor(lt, 32, 64);
    const float inv = 1.0f / lt;
    ushort* yrow = y + (size_t)(b * T_ + q0 + wid * 16 + l16) * (NH * HD) + h * HD;
    #pragma unroll
    for (int t = 0; t < 4; ++t) {
        ushort4 o;
        o.x = f2bf(oacc[t][0] * inv); o.y = f2bf(oacc[t][1] * inv);
        o.z = f2bf(oacc[t][2] * inv); o.w = f2bf(oacc[t][3] * inv);
        *(ushort4*)(yrow + t * 16 + quad * 4) = o;
    }
}

// ---------------- launcher ----------------
extern "C" void kernel_launch(void* const* d_in, const int* in_sizes, int n_in,
                              void* d_out, int out_size, void* d_ws, size_t ws_size,
                              hipStream_t stream)
{
    const float* x    = (const float*)d_in[0];
    const float* cosT = (const float*)d_in[1];
    const float* sinT = (const float*)d_in[2];
    const float* Wq   = (const float*)d_in[3];
    const float* Wk   = (const float*)d_in[4];
    const float* Wv   = (const float*)d_in[5];
    const float* Wo   = (const float*)d_in[6];
    float* out = (float*)d_out;

    const int M = B_ * T_;  // 4096
    ushort* xb     = (ushort*)d_ws;                       // 4096*1024
    ushort* qkv    = xb  + (size_t)M * C_;                // 4096*1536
    ushort* yb     = qkv + (size_t)M * QKVN;              // 4096*1024
    ushort* WqkvT  = yb  + (size_t)M * C_;                // 1536*1024
    ushort* WoT    = WqkvT + (size_t)QKVN * C_;           // 1024*1024
    ushort* vTbuf  = WoT + (size_t)C_ * C_;               // 2*256*2048

    dim3 blk(256);
    // converts + weight transposes, one launch
    prep<<<640 + (M * C_) / 1024, blk, 0, stream>>>(x, Wq, Wk, Wv, Wo, xb, WqkvT, WoT);
    // fused QKV projection: rope(+exp2 scale) epilogue, v written straight to vT
    gemm_bf16bt<true, true><<<dim3(QKVN / 64, M / 128), blk, 0, stream>>>(
        xb, WqkvT, qkv, vTbuf, cosT, sinT, M, QKVN, C_);
    // attention (XCD-swizzled, 1024 single-tile blocks heavy-first, V in regs)
    attn_mfma<<<1024, blk, 0, stream>>>(qkv, vTbuf, yb);
    // output projection (fp32 out)
    gemm_bf16bt<false, false><<<dim3(C_ / 64, M / 128), blk, 0, stream>>>(
        yb, WoT, out, nullptr, nullptr, nullptr, M, C_, C_);
}

// Round 6
// 171.516 us; speedup vs baseline: 1.2215x; 1.2215x over previous
//
#include <hip/hip_runtime.h>
#include <hip/hip_bf16.h>
#include <math.h>

#define NH   16
#define NKV  4
#define HD   64
#define B_   2
#define T_   2048
#define C_   1024
#define QKVN 1536   // fused q(1024) | k(256) | v(256)

typedef __attribute__((ext_vector_type(8))) short short8;
typedef __attribute__((ext_vector_type(4))) float v4f;

__device__ inline ushort f2bf(float f) {
    union { float f; uint32_t u; } v; v.f = f;
    uint32_t r = v.u + 0x7fffu + ((v.u >> 16) & 1u);
    return (ushort)(r >> 16);
}

// pack two f32 -> one dword of bf16
__device__ inline uint pk_bf16(float a, float b) {
#if __has_builtin(__builtin_amdgcn_cvt_pk_bf16_f32)
    auto v = __builtin_amdgcn_cvt_pk_bf16_f32(a, b);
    union { decltype(v) v2; uint u; } cv; cv.v2 = v; return cv.u;
#else
    return (uint)f2bf(a) | ((uint)f2bf(b) << 16);
#endif
}

__device__ inline float ex2(float x) {
#if __has_builtin(__builtin_amdgcn_exp2f)
    return __builtin_amdgcn_exp2f(x);
#else
    return exp2f(x);
#endif
}

// async global->LDS, 16B per lane; LDS dest wave-uniform base + lane*16
__device__ inline void async16(const void* g, void* l) {
    __builtin_amdgcn_global_load_lds(
        (const __attribute__((address_space(1))) unsigned int*)g,
        (__attribute__((address_space(3))) unsigned int*)l, 16, 0, 0);
}

// ---------------- prep: x f32->bf16 convert + 4 weight transposes ----------
__global__ __launch_bounds__(256) void prep(
    const float* __restrict__ x,
    const float* __restrict__ Wq, const float* __restrict__ Wk,
    const float* __restrict__ Wv, const float* __restrict__ Wo,
    ushort* __restrict__ xb, ushort* __restrict__ WqkvT, ushort* __restrict__ WoT)
{
    const int bx = blockIdx.x;
    const int tid = threadIdx.x;
    if (bx < 640) {
        __shared__ float tile[64][65];
        const int cb = bx >> 4;
        const int kb = bx & 15;
        const float* src; ushort* dst; int N, nb;
        if (cb < 16)      { src = Wq; dst = WqkvT;                     N = 1024; nb = cb; }
        else if (cb < 20) { src = Wk; dst = WqkvT + (size_t)1024 * C_; N = 256;  nb = cb - 16; }
        else if (cb < 24) { src = Wv; dst = WqkvT + (size_t)1280 * C_; N = 256;  nb = cb - 20; }
        else              { src = Wo; dst = WoT;                       N = 1024; nb = cb - 24; }
        const int k0 = kb * 64, n0 = nb * 64;
        #pragma unroll
        for (int it = 0; it < 4; ++it) {
            int r = (tid >> 4) + it * 16;
            int c = (tid & 15) * 4;
            float4 v = *(const float4*)(src + (size_t)(k0 + r) * N + n0 + c);
            tile[r][c] = v.x; tile[r][c + 1] = v.y; tile[r][c + 2] = v.z; tile[r][c + 3] = v.w;
        }
        __syncthreads();
        #pragma unroll
        for (int it = 0; it < 4; ++it) {
            int r = (tid >> 4) + it * 16;
            int c = (tid & 15) * 4;
            ushort4 o;
            o.x = f2bf(tile[c + 0][r]); o.y = f2bf(tile[c + 1][r]);
            o.z = f2bf(tile[c + 2][r]); o.w = f2bf(tile[c + 3][r]);
            *(ushort4*)(dst + (size_t)(n0 + r) * C_ + k0 + c) = o;
        }
    } else {
        int i = ((bx - 640) * 256 + tid) * 4;   // covers 4096*1024 exactly
        float4 v = *(const float4*)(x + i);
        ushort4 o; o.x = f2bf(v.x); o.y = f2bf(v.y); o.z = f2bf(v.z); o.w = f2bf(v.w);
        *(ushort4*)(xb + i) = o;
    }
}

// ---------------- bf16 MFMA GEMM: C[M,N] = A[M,K] @ Bt[N,K]^T --------------
// R17: prefetch depth 1 -> 2 (T4 counted-vmcnt). The old loop drained
// vmcnt(0) on a prefetch issued only ~1 iter (~250cy) earlier — L2/HBM
// latency partially exposed on EVERY of the 32 K-iters. Now 3 LDS buffers;
// per-iter wait is vmcnt(3) (keeps the newest stage-group of 3 DMAs in
// flight; the waited-for group was issued 2 iters ago). vmcnt(0) only on
// the last iter. WAR on buf[(it+2)%3] ordered by this iter's barrier.
// 128(M)x64(N) tile, BK=32, 4 waves along M (wave: 32m x 64n). LDS 36KB.
// ROPE path (QKV gemm): n0<1024 -> rope + 0.125*log2e scale (exp2 softmax);
// 1024..1279 -> rope only (k); n0>=1280 -> v stored transposed into vT.
template <bool BF16OUT, bool ROPE>
__global__ __launch_bounds__(256) void gemm_bf16bt(
    const ushort* __restrict__ A, const ushort* __restrict__ Bt,
    void* __restrict__ Cout, ushort* __restrict__ vTout,
    const float* __restrict__ cs, const float* __restrict__ sn,
    int M, int N, int K)
{
    __shared__ __align__(16) short As[3][128 * 32];
    __shared__ __align__(16) short Bs[3][64 * 32];

    const int tid  = threadIdx.x;
    const int lane = tid & 63;
    const int wid  = tid >> 6;
    const int l16  = lane & 15;
    const int quad = lane >> 4;
    const int m0   = blockIdx.y * 128;
    const int n0   = blockIdx.x * 64;

    const ushort* agb = A  + (size_t)(m0 + wid * 32 + (lane >> 2)) * K + (lane & 3) * 8;
    const ushort* bgb = Bt + (size_t)(n0 + wid * 16 + (lane >> 2)) * K + (lane & 3) * 8;

    v4f acc[2][4];
    #pragma unroll
    for (int i = 0; i < 2; ++i)
        #pragma unroll
        for (int j = 0; j < 4; ++j) acc[i][j] = (v4f){0.f, 0.f, 0.f, 0.f};

    const int nIter = K >> 5;
    // prologue: stage iters 0 and 1 (each stage = 3 DMAs, FIFO-grouped)
    async16(agb,                  &As[0][(wid * 32) * 32]);
    async16(agb + (size_t)16 * K, &As[0][(wid * 32 + 16) * 32]);
    async16(bgb,                  &Bs[0][(wid * 16) * 32]);
    if (nIter > 1) {
        async16(agb + 32,                  &As[1][(wid * 32) * 32]);
        async16(agb + 32 + (size_t)16 * K, &As[1][(wid * 32 + 16) * 32]);
        async16(bgb + 32,                  &Bs[1][(wid * 16) * 32]);
    }

    for (int it = 0; it < nIter; ++it) {
        // wait for buf[it%3]'s 3 DMAs (issued 2 iters ago); keep the newest
        // stage-group in flight. Publish via raw barrier.
        if (it + 1 < nIter)
            asm volatile("s_waitcnt vmcnt(3)\n\ts_barrier" ::: "memory");
        else
            asm volatile("s_waitcnt vmcnt(0)\n\ts_barrier" ::: "memory");

        // stage iter it+2 into buf[(it+2)%3] (that region's readers all
        // passed the barrier above).
        if (it + 2 < nIter) {
            const int nb = (it + 2) % 3;
            const int k0 = (it + 2) << 5;
            async16(agb + k0,                  &As[nb][(wid * 32) * 32]);
            async16(agb + k0 + (size_t)16 * K, &As[nb][(wid * 32 + 16) * 32]);
            async16(bgb + k0,                  &Bs[nb][(wid * 16) * 32]);
        }

        const short* Ab = As[it % 3];
        const short* Bb = Bs[it % 3];
        short8 af[2], bf[4];
        #pragma unroll
        for (int i = 0; i < 2; ++i)
            af[i] = *(const short8*)&Ab[(wid * 32 + i * 16 + l16) * 32 + quad * 8];
        #pragma unroll
        for (int j = 0; j < 4; ++j)
            bf[j] = *(const short8*)&Bb[(j * 16 + l16) * 32 + quad * 8];
        #pragma unroll
        for (int i = 0; i < 2; ++i)
            #pragma unroll
            for (int j = 0; j < 4; ++j)
                acc[i][j] = __builtin_amdgcn_mfma_f32_16x16x32_bf16(af[i], bf[j], acc[i][j], 0, 0, 0);
    }

    if (ROPE && n0 >= 1280) {
        // v tile: store transposed to vT[(b*256 + (col-1280))][t]
        #pragma unroll
        for (int i = 0; i < 2; ++i) {
            const int row = m0 + wid * 32 + i * 16 + quad * 4;   // 4 consecutive t
            const int bb  = row >> 11;
            const int t   = row & (T_ - 1);
            #pragma unroll
            for (int j = 0; j < 4; ++j) {
                const int vc = n0 - 1280 + j * 16 + l16;
                ushort4 o;
                o.x = f2bf(acc[i][j][0]); o.y = f2bf(acc[i][j][1]);
                o.z = f2bf(acc[i][j][2]); o.w = f2bf(acc[i][j][3]);
                *(ushort4*)(vTout + (size_t)(bb * 256 + vc) * T_ + t) = o;
            }
        }
        return;
    }

    if (ROPE) {
        // q gets 0.125 * log2(e) so attention works in exp2 domain
        const float qs = (n0 < 1024) ? 0.18033688f : 1.0f;
        #pragma unroll
        for (int i = 0; i < 2; ++i) {
            #pragma unroll
            for (int r = 0; r < 4; ++r) {
                const int row = m0 + wid * 32 + i * 16 + quad * 4 + r;
                const int t = row & (T_ - 1);
                #pragma unroll
                for (int j = 0; j < 2; ++j) {
                    const int d = j * 16 + l16;
                    float cv = cs[t * 32 + d] * qs, sv = sn[t * 32 + d] * qs;
                    float x1 = acc[i][j][r], x2 = acc[i][j + 2][r];
                    acc[i][j][r]     = x1 * cv - x2 * sv;
                    acc[i][j + 2][r] = x2 * cv + x1 * sv;
                }
            }
        }
    }

    #pragma unroll
    for (int i = 0; i < 2; ++i) {
        #pragma unroll
        for (int r = 0; r < 4; ++r) {
            const int row = m0 + wid * 32 + i * 16 + quad * 4 + r;
            #pragma unroll
            for (int j = 0; j < 4; ++j) {
                const int col = n0 + j * 16 + l16;
                if (BF16OUT)
                    ((ushort*)Cout)[(size_t)row * N + col] = f2bf(acc[i][j][r]);
                else
                    ((float*)Cout)[(size_t)row * N + col] = acc[i][j][r];
            }
        }
    }
}

// ---------------- MFMA flash attention: 128-key chunks, V via LDS ---------
// R17: verbatim revert to the R1 kernel (measured 48.0us, counters
// bit-stable across R0/R1) — the reg-staged-V experiments (R3-R5) all
// failed because the compiler sinks V loads to PV regardless of fences
// (cross-BB sinking; VGPR_Count stayed 84). This is the proven structure:
// grid 512 paired q-tiles, XCD swizzle, 128-key chunks, V staged via
// async16 with per-call swizzle, counted vmcnt(4) + raw-barrier V
// visibility, tree softmax + defer-max + per-lane partial l + setprio.
#define PSTR 136
__global__ __launch_bounds__(256, 2) void attn_mfma(
    const ushort* __restrict__ qkv, const ushort* __restrict__ vT,
    ushort* __restrict__ y)
{
    __shared__ __align__(16) short Ks[2][128 * 64];   // [key][d] 128B rows
    __shared__ __align__(16) short Vs[64 * 128];      // [d][key] 256B rows
    __shared__ __align__(16) short Ps[4][16][PSTR];

    const int tid  = threadIdx.x;
    const int wid  = tid >> 6;
    const int ln   = tid & 63;
    const int l16  = ln & 15;
    const int quad = ln >> 4;

    const int bi   = blockIdx.x;          // 0..511
    const int xcd  = bi & 7;
    const int b    = xcd >> 2;
    const int kvh  = xcd & 3;
    const int jj   = bi >> 3;             // 0..63
    const int h    = kvh * 4 + (jj & 3);
    const int pr   = jj >> 2;             // 0..15

    const ushort* kbase = qkv + (size_t)(b * T_) * QKVN + 1024 + kvh * HD;
    const ushort* vtb   = vT + (size_t)(b * 256 + kvh * HD) * T_;

    // K staging: wave stages rows r0..r0+31 (128B rows, 8 x16B blocks/row)
    const int r0   = wid * 32;
    const int srow = ln >> 3;                     // 0..7
    const int sblk = ((ln & 7) ^ srow) * 8;       // XOR-swizzled source col
    const int sl0  = (quad ^ (l16 & 7)) * 8;      // K frag slot, d-blocks 0..3
    const int sl1  = sl0 ^ 32;                    // d-blocks 4..7
    // V staging: wave stages d-rows vr0..vr0+15 (256B rows, 16 x16B blocks)
    const int vr0  = wid * 16;
    const int vrow = ln >> 4;                     // 0..3
    const int vs4  = ln & 15;                     // LDS slot within row

    #pragma unroll 1
    for (int pass = 0; pass < 2; ++pass) {
        const int tb = pass ? pr : (31 - pr);     // heavy tile first
        const int q0 = tb * 64;
        const int nch = tb / 2 + 1;               // 128-key chunks

        // Q B-fragments (pre-scaled by 0.125*log2e): B[n=l16][k=quad*8+j]
        short8 qf0, qf1;
        {
            const ushort* qrow = qkv + (size_t)(b * T_ + q0 + wid * 16 + l16) * QKVN + h * HD;
            qf0 = *(const short8*)(qrow + quad * 8);
            qf1 = *(const short8*)(qrow + 32 + quad * 8);
        }

        v4f oacc[4];
        #pragma unroll
        for (int t = 0; t < 4; ++t) oacc[t] = (v4f){0.f, 0.f, 0.f, 0.f};
        float m = -1e30f, l = 0.f;   // l: per-lane PARTIAL (this quad's keys)

        if (pass) __syncthreads();   // protect Ks/Vs reuse across passes

        // prologue: stage K chunk 0 (128 rows) into buf 0
        {
            const ushort* kg = kbase + (size_t)(r0 + srow) * QKVN + sblk;
            async16(kg,                     &Ks[0][(r0     ) * 64]);
            async16(kg + (size_t) 8 * QKVN, &Ks[0][(r0 +  8) * 64]);
            async16(kg + (size_t)16 * QKVN, &Ks[0][(r0 + 16) * 64]);
            async16(kg + (size_t)24 * QKVN, &Ks[0][(r0 + 24) * 64]);
        }

        for (int c = 0; c < nch; ++c) {
            const int key0 = c * 128;
            __syncthreads();   // per-wave vmcnt(0): K chunk-c DMA drained; V area free

            // stage V chunk c into LDS (single buffer). Swizzle: slot vs4 of
            // d-row d holds global key-block vs4 ^ (d&15); per-call offset.
            {
                const ushort* vg = vtb + (size_t)(vr0 + vrow) * T_ + key0;
                async16(vg                   + (vs4 ^ (vrow     )) * 8, &Vs[(vr0     ) * 128]);
                async16(vg + (size_t) 4 * T_ + (vs4 ^ (vrow +  4)) * 8, &Vs[(vr0 +  4) * 128]);
                async16(vg + (size_t) 8 * T_ + (vs4 ^ (vrow +  8)) * 8, &Vs[(vr0 +  8) * 128]);
                async16(vg + (size_t)12 * T_ + (vs4 ^ (vrow + 12)) * 8, &Vs[(vr0 + 12) * 128]);
            }
            // prefetch K chunk c+1
            const bool kpref = (c + 1 < nch);
            if (kpref) {
                const int nb = (c + 1) & 1;
                const ushort* kg = kbase + (size_t)(key0 + 128 + r0 + srow) * QKVN + sblk;
                async16(kg,                     &Ks[nb][(r0     ) * 64]);
                async16(kg + (size_t) 8 * QKVN, &Ks[nb][(r0 +  8) * 64]);
                async16(kg + (size_t)16 * QKVN, &Ks[nb][(r0 + 16) * 64]);
                async16(kg + (size_t)24 * QKVN, &Ks[nb][(r0 + 24) * 64]);
            }
            const short* Kb = Ks[c & 1];

            // ---- S^T = K @ Q^T (row=key, col=query), 8 key-tiles ----
            v4f st[8];
            __builtin_amdgcn_s_setprio(1);
            #pragma unroll
            for (int t = 0; t < 8; ++t) {
                short8 k0f = *(const short8*)&Kb[(t * 16 + l16) * 64 + sl0];
                short8 k1f = *(const short8*)&Kb[(t * 16 + l16) * 64 + sl1];
                v4f s = (v4f){0.f, 0.f, 0.f, 0.f};
                s = __builtin_amdgcn_mfma_f32_16x16x32_bf16(k0f, qf0, s, 0, 0, 0);
                s = __builtin_amdgcn_mfma_f32_16x16x32_bf16(k1f, qf1, s, 0, 0, 0);
                st[t] = s;
            }
            __builtin_amdgcn_s_setprio(0);

            // causal mask: only the chunk containing the diagonal
            if (c == nch - 1) {
                const int qg = wid * 16 + l16 + q0;
                #pragma unroll
                for (int t = 0; t < 8; ++t)
                    #pragma unroll
                    for (int r = 0; r < 4; ++r)
                        if (key0 + t * 16 + quad * 4 + r > qg) st[t][r] = -1e30f;
            }

            // ---- online softmax (exp2 domain), tree-reduced, defer-max ----
            float tm[8];
            #pragma unroll
            for (int t = 0; t < 8; ++t)
                tm[t] = fmaxf(fmaxf(st[t][0], st[t][1]), fmaxf(st[t][2], st[t][3]));
            float mx = fmaxf(fmaxf(fmaxf(tm[0], tm[1]), fmaxf(tm[2], tm[3])),
                             fmaxf(fmaxf(tm[4], tm[5]), fmaxf(tm[6], tm[7])));
            // common path: max grew by <= 8 for every lane -> keep old m,
            // skip cross-quad shfls and the whole rescale pass.
            if (!__all(mx <= m + 8.0f)) {
                float mf = fmaxf(mx, __shfl_xor(mx, 16, 64));
                mf = fmaxf(mf, __shfl_xor(mf, 32, 64));
                const float mnew  = fmaxf(m, mf);
                const float alpha = ex2(m - mnew);
                m = mnew;
                l *= alpha;
                #pragma unroll
                for (int t = 0; t < 4; ++t)
                    #pragma unroll
                    for (int r = 0; r < 4; ++r) oacc[t][r] *= alpha;
            }
            float p[8][4], ts[8];
            #pragma unroll
            for (int t = 0; t < 8; ++t) {
                p[t][0] = ex2(st[t][0] - m); p[t][1] = ex2(st[t][1] - m);
                p[t][2] = ex2(st[t][2] - m); p[t][3] = ex2(st[t][3] - m);
                ts[t] = (p[t][0] + p[t][1]) + (p[t][2] + p[t][3]);
            }
            l += ((ts[0] + ts[1]) + (ts[2] + ts[3])) +
                 ((ts[4] + ts[5]) + (ts[6] + ts[7]));

            // write P^T rows: Ps[query=l16][key], packed pairs -> b64
            #pragma unroll
            for (int t = 0; t < 8; ++t) {
                uint2 w;
                w.x = pk_bf16(p[t][0], p[t][1]);
                w.y = pk_bf16(p[t][2], p[t][3]);
                *(uint2*)&Ps[wid][l16][t * 16 + quad * 4] = w;
            }

            // drain this wave's P ds_writes
            asm volatile("s_waitcnt lgkmcnt(0)" ::: "memory");
            short8 pa[4];
            #pragma unroll
            for (int seg = 0; seg < 4; ++seg)
                pa[seg] = *(const short8*)&Ps[wid][l16][seg * 32 + quad * 8];

            // V visibility: drain own V DMAs (vmcnt(4) keeps K-prefetch in
            // flight; vmcnt(0) on last chunk), then RAW s_barrier so ALL
            // waves' V rows are visible.
            if (kpref) asm volatile("s_waitcnt vmcnt(4)\n\ts_barrier" ::: "memory");
            else       asm volatile("s_waitcnt vmcnt(0)\n\ts_barrier" ::: "memory");

            // ---- O^T += V^T @ P^T : V frags from LDS (swizzled rows) ----
            __builtin_amdgcn_s_setprio(1);
            #pragma unroll
            for (int t = 0; t < 4; ++t) {
                const int dr = t * 16 + l16;          // V d-row
                #pragma unroll
                for (int seg = 0; seg < 4; ++seg) {
                    const int slot = ((seg * 4 + quad) ^ dr) & 15;
                    short8 vv = *(const short8*)&Vs[dr * 128 + slot * 8];
                    oacc[t] = __builtin_amdgcn_mfma_f32_16x16x32_bf16(vv, pa[seg], oacc[t], 0, 0, 0);
                }
            }
            __builtin_amdgcn_s_setprio(0);
        }

        // epilogue: cross-quad reduce the partial l, then y = O^T / l
        float lt = l + __shfl_xor(l, 16, 64);
        lt += __shfl_xor(lt, 32, 64);
        const float inv = 1.0f / lt;
        ushort* yrow = y + (size_t)(b * T_ + q0 + wid * 16 + l16) * (NH * HD) + h * HD;
        #pragma unroll
        for (int t = 0; t < 4; ++t) {
            ushort4 o;
            o.x = f2bf(oacc[t][0] * inv); o.y = f2bf(oacc[t][1] * inv);
            o.z = f2bf(oacc[t][2] * inv); o.w = f2bf(oacc[t][3] * inv);
            *(ushort4*)(yrow + t * 16 + quad * 4) = o;
        }
    }
}

// ---------------- launcher ----------------
extern "C" void kernel_launch(void* const* d_in, const int* in_sizes, int n_in,
                              void* d_out, int out_size, void* d_ws, size_t ws_size,
                              hipStream_t stream)
{
    const float* x    = (const float*)d_in[0];
    const float* cosT = (const float*)d_in[1];
    const float* sinT = (const float*)d_in[2];
    const float* Wq   = (const float*)d_in[3];
    const float* Wk   = (const float*)d_in[4];
    const float* Wv   = (const float*)d_in[5];
    const float* Wo   = (const float*)d_in[6];
    float* out = (float*)d_out;

    const int M = B_ * T_;  // 4096
    ushort* xb     = (ushort*)d_ws;                       // 4096*1024
    ushort* qkv    = xb  + (size_t)M * C_;                // 4096*1536
    ushort* yb     = qkv + (size_t)M * QKVN;              // 4096*1024
    ushort* WqkvT  = yb  + (size_t)M * C_;                // 1536*1024
    ushort* WoT    = WqkvT + (size_t)QKVN * C_;           // 1024*1024
    ushort* vTbuf  = WoT + (size_t)C_ * C_;               // 2*256*2048

    dim3 blk(256);
    // converts + weight transposes, one launch
    prep<<<640 + (M * C_) / 1024, blk, 0, stream>>>(x, Wq, Wk, Wv, Wo, xb, WqkvT, WoT);
    // fused QKV projection: rope(+exp2 scale) epilogue, v written straight to vT
    gemm_bf16bt<true, true><<<dim3(QKVN / 64, M / 128), blk, 0, stream>>>(
        xb, WqkvT, qkv, vTbuf, cosT, sinT, M, QKVN, C_);
    // attention (XCD-swizzled, paired tiles, 128-key chunks, V via LDS)
    attn_mfma<<<512, blk, 0, stream>>>(qkv, vTbuf, yb);
    // output projection (fp32 out)
    gemm_bf16bt<false, false><<<dim3(C_ / 64, M / 128), blk, 0, stream>>>(
        yb, WoT, out, nullptr, nullptr, nullptr, M, C_, C_);
}

// Round 7
// 164.527 us; speedup vs baseline: 1.2734x; 1.0425x over previous
//
#include <hip/hip_runtime.h>
#include <hip/hip_bf16.h>
#include <math.h>

#define NH   16
#define NKV  4
#define HD   64
#define B_   2
#define T_   2048
#define C_   1024
#define QKVN 1536   // fused q(1024) | k(256) | v(256)

typedef __attribute__((ext_vector_type(8))) short short8;
typedef __attribute__((ext_vector_type(4))) float v4f;

__device__ inline ushort f2bf(float f) {
    union { float f; uint32_t u; } v; v.f = f;
    uint32_t r = v.u + 0x7fffu + ((v.u >> 16) & 1u);
    return (ushort)(r >> 16);
}

// pack two f32 -> one dword of bf16
__device__ inline uint pk_bf16(float a, float b) {
#if __has_builtin(__builtin_amdgcn_cvt_pk_bf16_f32)
    auto v = __builtin_amdgcn_cvt_pk_bf16_f32(a, b);
    union { decltype(v) v2; uint u; } cv; cv.v2 = v; return cv.u;
#else
    return (uint)f2bf(a) | ((uint)f2bf(b) << 16);
#endif
}

__device__ inline float ex2(float x) {
#if __has_builtin(__builtin_amdgcn_exp2f)
    return __builtin_amdgcn_exp2f(x);
#else
    return exp2f(x);
#endif
}

// async global->LDS, 16B per lane; LDS dest wave-uniform base + lane*16
__device__ inline void async16(const void* g, void* l) {
    __builtin_amdgcn_global_load_lds(
        (const __attribute__((address_space(1))) unsigned int*)g,
        (__attribute__((address_space(3))) unsigned int*)l, 16, 0, 0);
}

// ---------------- prep: x f32->bf16 convert + 4 weight transposes ----------
__global__ __launch_bounds__(256) void prep(
    const float* __restrict__ x,
    const float* __restrict__ Wq, const float* __restrict__ Wk,
    const float* __restrict__ Wv, const float* __restrict__ Wo,
    ushort* __restrict__ xb, ushort* __restrict__ WqkvT, ushort* __restrict__ WoT)
{
    const int bx = blockIdx.x;
    const int tid = threadIdx.x;
    if (bx < 640) {
        __shared__ float tile[64][65];
        const int cb = bx >> 4;
        const int kb = bx & 15;
        const float* src; ushort* dst; int N, nb;
        if (cb < 16)      { src = Wq; dst = WqkvT;                     N = 1024; nb = cb; }
        else if (cb < 20) { src = Wk; dst = WqkvT + (size_t)1024 * C_; N = 256;  nb = cb - 16; }
        else if (cb < 24) { src = Wv; dst = WqkvT + (size_t)1280 * C_; N = 256;  nb = cb - 20; }
        else              { src = Wo; dst = WoT;                       N = 1024; nb = cb - 24; }
        const int k0 = kb * 64, n0 = nb * 64;
        #pragma unroll
        for (int it = 0; it < 4; ++it) {
            int r = (tid >> 4) + it * 16;
            int c = (tid & 15) * 4;
            float4 v = *(const float4*)(src + (size_t)(k0 + r) * N + n0 + c);
            tile[r][c] = v.x; tile[r][c + 1] = v.y; tile[r][c + 2] = v.z; tile[r][c + 3] = v.w;
        }
        __syncthreads();
        #pragma unroll
        for (int it = 0; it < 4; ++it) {
            int r = (tid >> 4) + it * 16;
            int c = (tid & 15) * 4;
            ushort4 o;
            o.x = f2bf(tile[c + 0][r]); o.y = f2bf(tile[c + 1][r]);
            o.z = f2bf(tile[c + 2][r]); o.w = f2bf(tile[c + 3][r]);
            *(ushort4*)(dst + (size_t)(n0 + r) * C_ + k0 + c) = o;
        }
    } else {
        int i = ((bx - 640) * 256 + tid) * 4;   // covers 4096*1024 exactly
        float4 v = *(const float4*)(x + i);
        ushort4 o; o.x = f2bf(v.x); o.y = f2bf(v.y); o.z = f2bf(v.z); o.w = f2bf(v.w);
        *(ushort4*)(xb + i) = o;
    }
}

// ---------------- bf16 MFMA GEMM: C[M,N] = A[M,K] @ Bt[N,K]^T --------------
// R19: exact R0/R12 config (proven; depth-2 prefetch in R6 was neutral).
// 128(M)x64(N) tile, BK=32, 4 waves stacked along M (wave: 32m x 64n),
// double-buffered LDS, ONE raw barrier per iter, async global_load_lds
// prefetch in flight across the whole compute of iter i.
// ROPE path (QKV gemm): n0<1024 -> rope + 0.125*log2e scale (exp2 softmax);
// 1024..1279 -> rope only (k); n0>=1280 -> v stored transposed into vT.
template <bool BF16OUT, bool ROPE>
__global__ __launch_bounds__(256) void gemm_bf16bt(
    const ushort* __restrict__ A, const ushort* __restrict__ Bt,
    void* __restrict__ Cout, ushort* __restrict__ vTout,
    const float* __restrict__ cs, const float* __restrict__ sn,
    int M, int N, int K)
{
    __shared__ __align__(16) short As[2][128 * 32];
    __shared__ __align__(16) short Bs[2][64 * 32];

    const int tid  = threadIdx.x;
    const int lane = tid & 63;
    const int wid  = tid >> 6;
    const int l16  = lane & 15;
    const int quad = lane >> 4;
    const int m0   = blockIdx.y * 128;
    const int n0   = blockIdx.x * 64;

    const ushort* agb = A  + (size_t)(m0 + wid * 32 + (lane >> 2)) * K + (lane & 3) * 8;
    const ushort* bgb = Bt + (size_t)(n0 + wid * 16 + (lane >> 2)) * K + (lane & 3) * 8;

    v4f acc[2][4];
    #pragma unroll
    for (int i = 0; i < 2; ++i)
        #pragma unroll
        for (int j = 0; j < 4; ++j) acc[i][j] = (v4f){0.f, 0.f, 0.f, 0.f};

    // prologue: stage iter 0 into buf 0
    async16(agb,                  &As[0][(wid * 32) * 32]);
    async16(agb + (size_t)16 * K, &As[0][(wid * 32 + 16) * 32]);
    async16(bgb,                  &Bs[0][(wid * 16) * 32]);

    const int nIter = K >> 5;
    for (int it = 0; it < nIter; ++it) {
        // drain own buf-it DMA (only thing in flight), publish to block.
        asm volatile("s_waitcnt vmcnt(0)\n\ts_barrier" ::: "memory");

        // prefetch iter it+1 into the other buffer; in flight across compute.
        if (it + 1 < nIter) {
            const int nb = (it + 1) & 1;
            const int k0 = (it + 1) << 5;
            async16(agb + k0,                  &As[nb][(wid * 32) * 32]);
            async16(agb + k0 + (size_t)16 * K, &As[nb][(wid * 32 + 16) * 32]);
            async16(bgb + k0,                  &Bs[nb][(wid * 16) * 32]);
        }

        const short* Ab = As[it & 1];
        const short* Bb = Bs[it & 1];
        short8 af[2], bf[4];
        #pragma unroll
        for (int i = 0; i < 2; ++i)
            af[i] = *(const short8*)&Ab[(wid * 32 + i * 16 + l16) * 32 + quad * 8];
        #pragma unroll
        for (int j = 0; j < 4; ++j)
            bf[j] = *(const short8*)&Bb[(j * 16 + l16) * 32 + quad * 8];
        #pragma unroll
        for (int i = 0; i < 2; ++i)
            #pragma unroll
            for (int j = 0; j < 4; ++j)
                acc[i][j] = __builtin_amdgcn_mfma_f32_16x16x32_bf16(af[i], bf[j], acc[i][j], 0, 0, 0);
    }

    if (ROPE && n0 >= 1280) {
        // v tile: store transposed to vT[(b*256 + (col-1280))][t]
        #pragma unroll
        for (int i = 0; i < 2; ++i) {
            const int row = m0 + wid * 32 + i * 16 + quad * 4;   // 4 consecutive t
            const int bb  = row >> 11;
            const int t   = row & (T_ - 1);
            #pragma unroll
            for (int j = 0; j < 4; ++j) {
                const int vc = n0 - 1280 + j * 16 + l16;
                ushort4 o;
                o.x = f2bf(acc[i][j][0]); o.y = f2bf(acc[i][j][1]);
                o.z = f2bf(acc[i][j][2]); o.w = f2bf(acc[i][j][3]);
                *(ushort4*)(vTout + (size_t)(bb * 256 + vc) * T_ + t) = o;
            }
        }
        return;
    }

    if (ROPE) {
        // q gets 0.125 * log2(e) so attention works in exp2 domain
        const float qs = (n0 < 1024) ? 0.18033688f : 1.0f;
        #pragma unroll
        for (int i = 0; i < 2; ++i) {
            #pragma unroll
            for (int r = 0; r < 4; ++r) {
                const int row = m0 + wid * 32 + i * 16 + quad * 4 + r;
                const int t = row & (T_ - 1);
                #pragma unroll
                for (int j = 0; j < 2; ++j) {
                    const int d = j * 16 + l16;
                    float cv = cs[t * 32 + d] * qs, sv = sn[t * 32 + d] * qs;
                    float x1 = acc[i][j][r], x2 = acc[i][j + 2][r];
                    acc[i][j][r]     = x1 * cv - x2 * sv;
                    acc[i][j + 2][r] = x2 * cv + x1 * sv;
                }
            }
        }
    }

    #pragma unroll
    for (int i = 0; i < 2; ++i) {
        #pragma unroll
        for (int r = 0; r < 4; ++r) {
            const int row = m0 + wid * 32 + i * 16 + quad * 4 + r;
            #pragma unroll
            for (int j = 0; j < 4; ++j) {
                const int col = n0 + j * 16 + l16;
                if (BF16OUT)
                    ((ushort*)Cout)[(size_t)row * N + col] = f2bf(acc[i][j][r]);
                else
                    ((float*)Cout)[(size_t)row * N + col] = acc[i][j][r];
            }
        }
    }
}

// ---------------- MFMA flash attention: 128-key chunks -------------------
// R19: occupancy 2 -> 3 blocks/CU while KEEPING the proven LDS-staged V
// and P paths (R3-R5 proved V must stay in LDS; R14 proved the occupancy
// mechanism works at 50KB/grid-1024). Change: K single-buffered.
//   LDS: Ks 16K + Vs 16K + Ps 17K = 50176B -> 3 blocks/CU.
//   2 barriers/chunk (same as before), reordered:
//     barrier A (chunk top): waits K chunk-c DMA (only thing in flight),
//       publishes Ks; then stage V chunk c (4 DMAs, in flight across QK).
//     barrier B (pre-PV): waits V DMAs (vmcnt(0) - only V in flight),
//       publishes Vs; all waves are past their Ks reads here, so K chunk
//       c+1 DMA is issued AFTER barrier B (WAR-safe) and has the whole
//       PV section + loop latency to land before the next barrier A.
//   Grid 512 paired -> 1024 single-tile blocks, heavy tiles first (R14
//   mapping), XCD swizzle kept. __launch_bounds__(256,3).
#define PSTR 136
__global__ __launch_bounds__(256, 3) void attn_mfma(
    const ushort* __restrict__ qkv, const ushort* __restrict__ vT,
    ushort* __restrict__ y)
{
    __shared__ __align__(16) short Ks[128 * 64];      // [key][d] 128B rows
    __shared__ __align__(16) short Vs[64 * 128];      // [d][key] 256B rows
    __shared__ __align__(16) short Ps[4][16][PSTR];

    const int tid  = threadIdx.x;
    const int wid  = tid >> 6;
    const int ln   = tid & 63;
    const int l16  = ln & 15;
    const int quad = ln >> 4;

    const int bi   = blockIdx.x;          // 0..1023
    const int xcd  = bi & 7;
    const int b    = xcd >> 2;
    const int kvh  = xcd & 3;
    const int jj   = bi >> 3;             // 0..127
    const int h    = kvh * 4 + (jj & 3);
    const int tb   = 31 - (jj >> 2);      // heavy tiles first

    const ushort* kbase = qkv + (size_t)(b * T_) * QKVN + 1024 + kvh * HD;
    const ushort* vtb   = vT + (size_t)(b * 256 + kvh * HD) * T_;

    // K staging: wave stages rows r0..r0+31 (128B rows, 8 x16B blocks/row)
    const int r0   = wid * 32;
    const int srow = ln >> 3;                     // 0..7
    const int sblk = ((ln & 7) ^ srow) * 8;       // XOR-swizzled source col
    const int sl0  = (quad ^ (l16 & 7)) * 8;      // K frag slot, d-blocks 0..3
    const int sl1  = sl0 ^ 32;                    // d-blocks 4..7
    // V staging: wave stages d-rows vr0..vr0+15 (256B rows, 16 x16B blocks)
    const int vr0  = wid * 16;
    const int vrow = ln >> 4;                     // 0..3
    const int vs4  = ln & 15;                     // LDS slot within row

    const int q0  = tb * 64;
    const int nch = tb / 2 + 1;               // 128-key chunks

    // Q B-fragments (pre-scaled by 0.125*log2e): B[n=l16][k=quad*8+j]
    short8 qf0, qf1;
    {
        const ushort* qrow = qkv + (size_t)(b * T_ + q0 + wid * 16 + l16) * QKVN + h * HD;
        qf0 = *(const short8*)(qrow + quad * 8);
        qf1 = *(const short8*)(qrow + 32 + quad * 8);
    }

    v4f oacc[4];
    #pragma unroll
    for (int t = 0; t < 4; ++t) oacc[t] = (v4f){0.f, 0.f, 0.f, 0.f};
    float m = -1e30f, l = 0.f;   // l: per-lane PARTIAL (this quad's keys)

    // prologue: stage K chunk 0
    {
        const ushort* kg = kbase + (size_t)(r0 + srow) * QKVN + sblk;
        async16(kg,                     &Ks[(r0     ) * 64]);
        async16(kg + (size_t) 8 * QKVN, &Ks[(r0 +  8) * 64]);
        async16(kg + (size_t)16 * QKVN, &Ks[(r0 + 16) * 64]);
        async16(kg + (size_t)24 * QKVN, &Ks[(r0 + 24) * 64]);
    }

    for (int c = 0; c < nch; ++c) {
        const int key0 = c * 128;

        // barrier A: own K chunk-c DMA is the only VMEM in flight; drain it
        // (+ lgkm so prev-chunk PV ds_reads are done before Vs overwrite),
        // then publish Ks to the block.
        asm volatile("s_waitcnt vmcnt(0) lgkmcnt(0)\n\ts_barrier" ::: "memory");

        // stage V chunk c into LDS; in flight across QK + softmax.
        // Swizzle: slot vs4 of d-row d holds global key-block vs4 ^ (d&15).
        {
            const ushort* vg = vtb + (size_t)(vr0 + vrow) * T_ + key0;
            async16(vg                   + (vs4 ^ (vrow     )) * 8, &Vs[(vr0     ) * 128]);
            async16(vg + (size_t) 4 * T_ + (vs4 ^ (vrow +  4)) * 8, &Vs[(vr0 +  4) * 128]);
            async16(vg + (size_t) 8 * T_ + (vs4 ^ (vrow +  8)) * 8, &Vs[(vr0 +  8) * 128]);
            async16(vg + (size_t)12 * T_ + (vs4 ^ (vrow + 12)) * 8, &Vs[(vr0 + 12) * 128]);
        }

        // ---- S^T = K @ Q^T (row=key, col=query), 8 key-tiles ----
        v4f st[8];
        __builtin_amdgcn_s_setprio(1);
        #pragma unroll
        for (int t = 0; t < 8; ++t) {
            short8 k0f = *(const short8*)&Ks[(t * 16 + l16) * 64 + sl0];
            short8 k1f = *(const short8*)&Ks[(t * 16 + l16) * 64 + sl1];
            v4f s = (v4f){0.f, 0.f, 0.f, 0.f};
            s = __builtin_amdgcn_mfma_f32_16x16x32_bf16(k0f, qf0, s, 0, 0, 0);
            s = __builtin_amdgcn_mfma_f32_16x16x32_bf16(k1f, qf1, s, 0, 0, 0);
            st[t] = s;
        }
        __builtin_amdgcn_s_setprio(0);

        // causal mask: only the chunk containing the diagonal
        if (c == nch - 1) {
            const int qg = wid * 16 + l16 + q0;
            #pragma unroll
            for (int t = 0; t < 8; ++t)
                #pragma unroll
                for (int r = 0; r < 4; ++r)
                    if (key0 + t * 16 + quad * 4 + r > qg) st[t][r] = -1e30f;
        }

        // ---- online softmax (exp2 domain), tree-reduced, defer-max ----
        float tm[8];
        #pragma unroll
        for (int t = 0; t < 8; ++t)
            tm[t] = fmaxf(fmaxf(st[t][0], st[t][1]), fmaxf(st[t][2], st[t][3]));
        float mx = fmaxf(fmaxf(fmaxf(tm[0], tm[1]), fmaxf(tm[2], tm[3])),
                         fmaxf(fmaxf(tm[4], tm[5]), fmaxf(tm[6], tm[7])));
        // common path: max grew by <= 8 for every lane -> keep old m,
        // skip cross-quad shfls and the whole rescale pass.
        if (!__all(mx <= m + 8.0f)) {
            float mf = fmaxf(mx, __shfl_xor(mx, 16, 64));
            mf = fmaxf(mf, __shfl_xor(mf, 32, 64));
            const float mnew  = fmaxf(m, mf);
            const float alpha = ex2(m - mnew);
            m = mnew;
            l *= alpha;
            #pragma unroll
            for (int t = 0; t < 4; ++t)
                #pragma unroll
                for (int r = 0; r < 4; ++r) oacc[t][r] *= alpha;
        }
        float p[8][4], ts[8];
        #pragma unroll
        for (int t = 0; t < 8; ++t) {
            p[t][0] = ex2(st[t][0] - m); p[t][1] = ex2(st[t][1] - m);
            p[t][2] = ex2(st[t][2] - m); p[t][3] = ex2(st[t][3] - m);
            ts[t] = (p[t][0] + p[t][1]) + (p[t][2] + p[t][3]);
        }
        l += ((ts[0] + ts[1]) + (ts[2] + ts[3])) +
             ((ts[4] + ts[5]) + (ts[6] + ts[7]));

        // write P^T rows: Ps[query=l16][key], packed pairs -> b64
        #pragma unroll
        for (int t = 0; t < 8; ++t) {
            uint2 w;
            w.x = pk_bf16(p[t][0], p[t][1]);
            w.y = pk_bf16(p[t][2], p[t][3]);
            *(uint2*)&Ps[wid][l16][t * 16 + quad * 4] = w;
        }

        // drain this wave's P ds_writes, read own P fragments (per-wave
        // scratch -> no barrier needed)
        asm volatile("s_waitcnt lgkmcnt(0)" ::: "memory");
        short8 pa[4];
        #pragma unroll
        for (int seg = 0; seg < 4; ++seg)
            pa[seg] = *(const short8*)&Ps[wid][l16][seg * 32 + quad * 8];

        // barrier B: V DMAs are the only VMEM in flight -> vmcnt(0) drains
        // them; s_barrier makes ALL waves' V rows visible. All waves are
        // past their Ks reads here (lgkm drained above), so Ks is free.
        asm volatile("s_waitcnt vmcnt(0)\n\ts_barrier" ::: "memory");

        // issue K chunk c+1 into Ks (WAR-safe after barrier B); in flight
        // across PV + loop-around, drained at the next barrier A.
        if (c + 1 < nch) {
            const ushort* kg = kbase + (size_t)(key0 + 128 + r0 + srow) * QKVN + sblk;
            async16(kg,                     &Ks[(r0     ) * 64]);
            async16(kg + (size_t) 8 * QKVN, &Ks[(r0 +  8) * 64]);
            async16(kg + (size_t)16 * QKVN, &Ks[(r0 + 16) * 64]);
            async16(kg + (size_t)24 * QKVN, &Ks[(r0 + 24) * 64]);
        }

        // ---- O^T += V^T @ P^T : V frags from LDS (swizzled rows) ----
        __builtin_amdgcn_s_setprio(1);
        #pragma unroll
        for (int t = 0; t < 4; ++t) {
            const int dr = t * 16 + l16;          // V d-row
            #pragma unroll
            for (int seg = 0; seg < 4; ++seg) {
                const int slot = ((seg * 4 + quad) ^ dr) & 15;
                short8 vv = *(const short8*)&Vs[dr * 128 + slot * 8];
                oacc[t] = __builtin_amdgcn_mfma_f32_16x16x32_bf16(vv, pa[seg], oacc[t], 0, 0, 0);
            }
        }
        __builtin_amdgcn_s_setprio(0);
    }

    // epilogue: cross-quad reduce the partial l, then y = O^T / l
    float lt = l + __shfl_xor(l, 16, 64);
    lt += __shfl_xor(lt, 32, 64);
    const float inv = 1.0f / lt;
    ushort* yrow = y + (size_t)(b * T_ + q0 + wid * 16 + l16) * (NH * HD) + h * HD;
    #pragma unroll
    for (int t = 0; t < 4; ++t) {
        ushort4 o;
        o.x = f2bf(oacc[t][0] * inv); o.y = f2bf(oacc[t][1] * inv);
        o.z = f2bf(oacc[t][2] * inv); o.w = f2bf(oacc[t][3] * inv);
        *(ushort4*)(yrow + t * 16 + quad * 4) = o;
    }
}

// ---------------- launcher ----------------
extern "C" void kernel_launch(void* const* d_in, const int* in_sizes, int n_in,
                              void* d_out, int out_size, void* d_ws, size_t ws_size,
                              hipStream_t stream)
{
    const float* x    = (const float*)d_in[0];
    const float* cosT = (const float*)d_in[1];
    const float* sinT = (const float*)d_in[2];
    const float* Wq   = (const float*)d_in[3];
    const float* Wk   = (const float*)d_in[4];
    const float* Wv   = (const float*)d_in[5];
    const float* Wo   = (const float*)d_in[6];
    float* out = (float*)d_out;

    const int M = B_ * T_;  // 4096
    ushort* xb     = (ushort*)d_ws;                       // 4096*1024
    ushort* qkv    = xb  + (size_t)M * C_;                // 4096*1536
    ushort* yb     = qkv + (size_t)M * QKVN;              // 4096*1024
    ushort* WqkvT  = yb  + (size_t)M * C_;                // 1536*1024
    ushort* WoT    = WqkvT + (size_t)QKVN * C_;           // 1024*1024
    ushort* vTbuf  = WoT + (size_t)C_ * C_;               // 2*256*2048

    dim3 blk(256);
    // converts + weight transposes, one launch
    prep<<<640 + (M * C_) / 1024, blk, 0, stream>>>(x, Wq, Wk, Wv, Wo, xb, WqkvT, WoT);
    // fused QKV projection: rope(+exp2 scale) epilogue, v written straight to vT
    gemm_bf16bt<true, true><<<dim3(QKVN / 64, M / 128), blk, 0, stream>>>(
        xb, WqkvT, qkv, vTbuf, cosT, sinT, M, QKVN, C_);
    // attention (XCD-swizzled, 1024 single-tile blocks heavy-first,
    // single-buffer K, 3 blocks/CU)
    attn_mfma<<<1024, blk, 0, stream>>>(qkv, vTbuf, yb);
    // output projection (fp32 out)
    gemm_bf16bt<false, false><<<dim3(C_ / 64, M / 128), blk, 0, stream>>>(
        yb, WoT, out, nullptr, nullptr, nullptr, M, C_, C_);
}

// Round 8
// 154.141 us; speedup vs baseline: 1.3592x; 1.0674x over previous
//
#include <hip/hip_runtime.h>
#include <hip/hip_bf16.h>
#include <math.h>

#define NH   16
#define NKV  4
#define HD   64
#define B_   2
#define T_   2048
#define C_   1024
#define QKVN 1536   // fused q(1024) | k(256) | v(256)

typedef __attribute__((ext_vector_type(8))) short short8;
typedef __attribute__((ext_vector_type(4))) float v4f;

__device__ inline ushort f2bf(float f) {
    union { float f; uint32_t u; } v; v.f = f;
    uint32_t r = v.u + 0x7fffu + ((v.u >> 16) & 1u);
    return (ushort)(r >> 16);
}

// pack two f32 -> one dword of bf16
__device__ inline uint pk_bf16(float a, float b) {
#if __has_builtin(__builtin_amdgcn_cvt_pk_bf16_f32)
    auto v = __builtin_amdgcn_cvt_pk_bf16_f32(a, b);
    union { decltype(v) v2; uint u; } cv; cv.v2 = v; return cv.u;
#else
    return (uint)f2bf(a) | ((uint)f2bf(b) << 16);
#endif
}

__device__ inline float ex2(float x) {
#if __has_builtin(__builtin_amdgcn_exp2f)
    return __builtin_amdgcn_exp2f(x);
#else
    return exp2f(x);
#endif
}

// async global->LDS, 16B per lane; LDS dest wave-uniform base + lane*16
__device__ inline void async16(const void* g, void* l) {
    __builtin_amdgcn_global_load_lds(
        (const __attribute__((address_space(1))) unsigned int*)g,
        (__attribute__((address_space(3))) unsigned int*)l, 16, 0, 0);
}

// ---------------- prep: x f32->bf16 convert + 4 weight transposes ----------
__global__ __launch_bounds__(256) void prep(
    const float* __restrict__ x,
    const float* __restrict__ Wq, const float* __restrict__ Wk,
    const float* __restrict__ Wv, const float* __restrict__ Wo,
    ushort* __restrict__ xb, ushort* __restrict__ WqkvT, ushort* __restrict__ WoT)
{
    const int bx = blockIdx.x;
    const int tid = threadIdx.x;
    if (bx < 640) {
        __shared__ float tile[64][65];
        const int cb = bx >> 4;
        const int kb = bx & 15;
        const float* src; ushort* dst; int N, nb;
        if (cb < 16)      { src = Wq; dst = WqkvT;                     N = 1024; nb = cb; }
        else if (cb < 20) { src = Wk; dst = WqkvT + (size_t)1024 * C_; N = 256;  nb = cb - 16; }
        else if (cb < 24) { src = Wv; dst = WqkvT + (size_t)1280 * C_; N = 256;  nb = cb - 20; }
        else              { src = Wo; dst = WoT;                       N = 1024; nb = cb - 24; }
        const int k0 = kb * 64, n0 = nb * 64;
        #pragma unroll
        for (int it = 0; it < 4; ++it) {
            int r = (tid >> 4) + it * 16;
            int c = (tid & 15) * 4;
            float4 v = *(const float4*)(src + (size_t)(k0 + r) * N + n0 + c);
            tile[r][c] = v.x; tile[r][c + 1] = v.y; tile[r][c + 2] = v.z; tile[r][c + 3] = v.w;
        }
        __syncthreads();
        #pragma unroll
        for (int it = 0; it < 4; ++it) {
            int r = (tid >> 4) + it * 16;
            int c = (tid & 15) * 4;
            ushort4 o;
            o.x = f2bf(tile[c + 0][r]); o.y = f2bf(tile[c + 1][r]);
            o.z = f2bf(tile[c + 2][r]); o.w = f2bf(tile[c + 3][r]);
            *(ushort4*)(dst + (size_t)(n0 + r) * C_ + k0 + c) = o;
        }
    } else {
        int i = ((bx - 640) * 256 + tid) * 4;   // covers 4096*1024 exactly
        float4 v = *(const float4*)(x + i);
        ushort4 o; o.x = f2bf(v.x); o.y = f2bf(v.y); o.z = f2bf(v.z); o.w = f2bf(v.w);
        *(ushort4*)(xb + i) = o;
    }
}

// ---------------- bf16 MFMA GEMM: C[M,N] = A[M,K] @ Bt[N,K]^T --------------
// R20: BK 32 -> 64 with the attn-proven XOR swizzle on the LDS tiles.
// Fixes two measured/derived defects of the old loop:
//  1) un-swizzled fragment reads were an 8-way bank conflict (row stride
//     64B; 16 lanes/quad-group -> 8 lanes/bank). Now: source col-block
//     pre-swizzled (((ln&7)^row)*8, m173 pattern), read slot = blk^(row&7)
//     -> 2 lanes/slot = conflict-free (m136).
//  2) 32 barrier+vmcnt(0) drains -> 16 (T3: amortize the drain).
// Per iter: 32 MFMA vs 12 ds_read_b128 (was 16 vs 6 per 2 iters).
// LDS 48KB -> still 3 blocks/CU. Same single-raw-barrier + global_load_lds
// prefetch pipeline; identical acc layout/epilogues.
// ROPE path (QKV gemm): n0<1024 -> rope + 0.125*log2e scale (exp2 softmax);
// 1024..1279 -> rope only (k); n0>=1280 -> v stored transposed into vT.
template <bool BF16OUT, bool ROPE>
__global__ __launch_bounds__(256) void gemm_bf16bt(
    const ushort* __restrict__ A, const ushort* __restrict__ Bt,
    void* __restrict__ Cout, ushort* __restrict__ vTout,
    const float* __restrict__ cs, const float* __restrict__ sn,
    int M, int N, int K)
{
    __shared__ __align__(16) short As[2][128 * 64];   // rows of 64 shorts (128B)
    __shared__ __align__(16) short Bs[2][64 * 64];

    const int tid  = threadIdx.x;
    const int lane = tid & 63;
    const int wid  = tid >> 6;
    const int l16  = lane & 15;
    const int quad = lane >> 4;
    const int m0   = blockIdx.y * 128;
    const int n0   = blockIdx.x * 64;

    const int srow = lane >> 3;                   // 0..7 (8 lanes per 128B row)
    const int sblk = ((lane & 7) ^ srow) * 8;     // XOR-swizzled source col (shorts)

    // each async16 call stages 8 consecutive rows (64 lanes x 16B = 1KB)
    const ushort* agb = A  + (size_t)(m0 + wid * 32 + srow) * K + sblk;
    const ushort* bgb = Bt + (size_t)(n0 + wid * 16 + srow) * K + sblk;

    v4f acc[2][4];
    #pragma unroll
    for (int i = 0; i < 2; ++i)
        #pragma unroll
        for (int j = 0; j < 4; ++j) acc[i][j] = (v4f){0.f, 0.f, 0.f, 0.f};

    // prologue: stage iter 0 into buf 0 (A: 4 calls, B: 2 calls per wave)
    async16(agb,                  &As[0][(wid * 32     ) * 64]);
    async16(agb + (size_t) 8 * K, &As[0][(wid * 32 +  8) * 64]);
    async16(agb + (size_t)16 * K, &As[0][(wid * 32 + 16) * 64]);
    async16(agb + (size_t)24 * K, &As[0][(wid * 32 + 24) * 64]);
    async16(bgb,                  &Bs[0][(wid * 16     ) * 64]);
    async16(bgb + (size_t) 8 * K, &Bs[0][(wid * 16 +  8) * 64]);

    const int nIter = K >> 6;
    for (int it = 0; it < nIter; ++it) {
        // drain own buf-it DMAs (only thing in flight), publish to block.
        asm volatile("s_waitcnt vmcnt(0)\n\ts_barrier" ::: "memory");

        // prefetch iter it+1 into the other buffer; in flight across compute.
        if (it + 1 < nIter) {
            const int nb = (it + 1) & 1;
            const int k0 = (it + 1) << 6;
            async16(agb + k0,                  &As[nb][(wid * 32     ) * 64]);
            async16(agb + k0 + (size_t) 8 * K, &As[nb][(wid * 32 +  8) * 64]);
            async16(agb + k0 + (size_t)16 * K, &As[nb][(wid * 32 + 16) * 64]);
            async16(agb + k0 + (size_t)24 * K, &As[nb][(wid * 32 + 24) * 64]);
            async16(bgb + k0,                  &Bs[nb][(wid * 16     ) * 64]);
            async16(bgb + k0 + (size_t) 8 * K, &Bs[nb][(wid * 16 +  8) * 64]);
        }

        const short* Ab = As[it & 1];
        const short* Bb = Bs[it & 1];
        // fragment reads: row r holds global block b at slot b^(r&7).
        // af[i][h]: k-block = h*4+quad; row = wid*32 + i*16 + l16 (r&7 = l16&7)
        short8 af[2][2], bf[4][2];
        #pragma unroll
        for (int i = 0; i < 2; ++i)
            #pragma unroll
            for (int h = 0; h < 2; ++h)
                af[i][h] = *(const short8*)&Ab[(wid * 32 + i * 16 + l16) * 64 +
                                               ((((h << 2) + quad)) ^ (l16 & 7)) * 8];
        #pragma unroll
        for (int j = 0; j < 4; ++j)
            #pragma unroll
            for (int h = 0; h < 2; ++h)
                bf[j][h] = *(const short8*)&Bb[(j * 16 + l16) * 64 +
                                               ((((h << 2) + quad)) ^ (l16 & 7)) * 8];
        #pragma unroll
        for (int h = 0; h < 2; ++h)
            #pragma unroll
            for (int i = 0; i < 2; ++i)
                #pragma unroll
                for (int j = 0; j < 4; ++j)
                    acc[i][j] = __builtin_amdgcn_mfma_f32_16x16x32_bf16(af[i][h], bf[j][h], acc[i][j], 0, 0, 0);
    }

    if (ROPE && n0 >= 1280) {
        // v tile: store transposed to vT[(b*256 + (col-1280))][t]
        #pragma unroll
        for (int i = 0; i < 2; ++i) {
            const int row = m0 + wid * 32 + i * 16 + quad * 4;   // 4 consecutive t
            const int bb  = row >> 11;
            const int t   = row & (T_ - 1);
            #pragma unroll
            for (int j = 0; j < 4; ++j) {
                const int vc = n0 - 1280 + j * 16 + l16;
                ushort4 o;
                o.x = f2bf(acc[i][j][0]); o.y = f2bf(acc[i][j][1]);
                o.z = f2bf(acc[i][j][2]); o.w = f2bf(acc[i][j][3]);
                *(ushort4*)(vTout + (size_t)(bb * 256 + vc) * T_ + t) = o;
            }
        }
        return;
    }

    if (ROPE) {
        // q gets 0.125 * log2(e) so attention works in exp2 domain
        const float qs = (n0 < 1024) ? 0.18033688f : 1.0f;
        #pragma unroll
        for (int i = 0; i < 2; ++i) {
            #pragma unroll
            for (int r = 0; r < 4; ++r) {
                const int row = m0 + wid * 32 + i * 16 + quad * 4 + r;
                const int t = row & (T_ - 1);
                #pragma unroll
                for (int j = 0; j < 2; ++j) {
                    const int d = j * 16 + l16;
                    float cv = cs[t * 32 + d] * qs, sv = sn[t * 32 + d] * qs;
                    float x1 = acc[i][j][r], x2 = acc[i][j + 2][r];
                    acc[i][j][r]     = x1 * cv - x2 * sv;
                    acc[i][j + 2][r] = x2 * cv + x1 * sv;
                }
            }
        }
    }

    #pragma unroll
    for (int i = 0; i < 2; ++i) {
        #pragma unroll
        for (int r = 0; r < 4; ++r) {
            const int row = m0 + wid * 32 + i * 16 + quad * 4 + r;
            #pragma unroll
            for (int j = 0; j < 4; ++j) {
                const int col = n0 + j * 16 + l16;
                if (BF16OUT)
                    ((ushort*)Cout)[(size_t)row * N + col] = f2bf(acc[i][j][r]);
                else
                    ((float*)Cout)[(size_t)row * N + col] = acc[i][j][r];
            }
        }
    }
}

// ---------------- MFMA flash attention: 128-key chunks -------------------
// R20: verbatim R7 kernel (new best — attn dropped below the 44us fills).
// Occupancy 3 blocks/CU via single-buffered K; LDS-staged V and P paths
// (proven); 2 barriers/chunk; K chunk c+1 issued after barrier B with the
// whole PV section to land; grid 1024 single-tile blocks heavy-first,
// XCD swizzle.
#define PSTR 136
__global__ __launch_bounds__(256, 3) void attn_mfma(
    const ushort* __restrict__ qkv, const ushort* __restrict__ vT,
    ushort* __restrict__ y)
{
    __shared__ __align__(16) short Ks[128 * 64];      // [key][d] 128B rows
    __shared__ __align__(16) short Vs[64 * 128];      // [d][key] 256B rows
    __shared__ __align__(16) short Ps[4][16][PSTR];

    const int tid  = threadIdx.x;
    const int wid  = tid >> 6;
    const int ln   = tid & 63;
    const int l16  = ln & 15;
    const int quad = ln >> 4;

    const int bi   = blockIdx.x;          // 0..1023
    const int xcd  = bi & 7;
    const int b    = xcd >> 2;
    const int kvh  = xcd & 3;
    const int jj   = bi >> 3;             // 0..127
    const int h    = kvh * 4 + (jj & 3);
    const int tb   = 31 - (jj >> 2);      // heavy tiles first

    const ushort* kbase = qkv + (size_t)(b * T_) * QKVN + 1024 + kvh * HD;
    const ushort* vtb   = vT + (size_t)(b * 256 + kvh * HD) * T_;

    // K staging: wave stages rows r0..r0+31 (128B rows, 8 x16B blocks/row)
    const int r0   = wid * 32;
    const int srow = ln >> 3;                     // 0..7
    const int sblk = ((ln & 7) ^ srow) * 8;       // XOR-swizzled source col
    const int sl0  = (quad ^ (l16 & 7)) * 8;      // K frag slot, d-blocks 0..3
    const int sl1  = sl0 ^ 32;                    // d-blocks 4..7
    // V staging: wave stages d-rows vr0..vr0+15 (256B rows, 16 x16B blocks)
    const int vr0  = wid * 16;
    const int vrow = ln >> 4;                     // 0..3
    const int vs4  = ln & 15;                     // LDS slot within row

    const int q0  = tb * 64;
    const int nch = tb / 2 + 1;               // 128-key chunks

    // Q B-fragments (pre-scaled by 0.125*log2e): B[n=l16][k=quad*8+j]
    short8 qf0, qf1;
    {
        const ushort* qrow = qkv + (size_t)(b * T_ + q0 + wid * 16 + l16) * QKVN + h * HD;
        qf0 = *(const short8*)(qrow + quad * 8);
        qf1 = *(const short8*)(qrow + 32 + quad * 8);
    }

    v4f oacc[4];
    #pragma unroll
    for (int t = 0; t < 4; ++t) oacc[t] = (v4f){0.f, 0.f, 0.f, 0.f};
    float m = -1e30f, l = 0.f;   // l: per-lane PARTIAL (this quad's keys)

    // prologue: stage K chunk 0
    {
        const ushort* kg = kbase + (size_t)(r0 + srow) * QKVN + sblk;
        async16(kg,                     &Ks[(r0     ) * 64]);
        async16(kg + (size_t) 8 * QKVN, &Ks[(r0 +  8) * 64]);
        async16(kg + (size_t)16 * QKVN, &Ks[(r0 + 16) * 64]);
        async16(kg + (size_t)24 * QKVN, &Ks[(r0 + 24) * 64]);
    }

    for (int c = 0; c < nch; ++c) {
        const int key0 = c * 128;

        // barrier A: own K chunk-c DMA is the only VMEM in flight; drain it
        // (+ lgkm so prev-chunk PV ds_reads are done before Vs overwrite),
        // then publish Ks to the block.
        asm volatile("s_waitcnt vmcnt(0) lgkmcnt(0)\n\ts_barrier" ::: "memory");

        // stage V chunk c into LDS; in flight across QK + softmax.
        // Swizzle: slot vs4 of d-row d holds global key-block vs4 ^ (d&15).
        {
            const ushort* vg = vtb + (size_t)(vr0 + vrow) * T_ + key0;
            async16(vg                   + (vs4 ^ (vrow     )) * 8, &Vs[(vr0     ) * 128]);
            async16(vg + (size_t) 4 * T_ + (vs4 ^ (vrow +  4)) * 8, &Vs[(vr0 +  4) * 128]);
            async16(vg + (size_t) 8 * T_ + (vs4 ^ (vrow +  8)) * 8, &Vs[(vr0 +  8) * 128]);
            async16(vg + (size_t)12 * T_ + (vs4 ^ (vrow + 12)) * 8, &Vs[(vr0 + 12) * 128]);
        }

        // ---- S^T = K @ Q^T (row=key, col=query), 8 key-tiles ----
        v4f st[8];
        __builtin_amdgcn_s_setprio(1);
        #pragma unroll
        for (int t = 0; t < 8; ++t) {
            short8 k0f = *(const short8*)&Ks[(t * 16 + l16) * 64 + sl0];
            short8 k1f = *(const short8*)&Ks[(t * 16 + l16) * 64 + sl1];
            v4f s = (v4f){0.f, 0.f, 0.f, 0.f};
            s = __builtin_amdgcn_mfma_f32_16x16x32_bf16(k0f, qf0, s, 0, 0, 0);
            s = __builtin_amdgcn_mfma_f32_16x16x32_bf16(k1f, qf1, s, 0, 0, 0);
            st[t] = s;
        }
        __builtin_amdgcn_s_setprio(0);

        // causal mask: only the chunk containing the diagonal
        if (c == nch - 1) {
            const int qg = wid * 16 + l16 + q0;
            #pragma unroll
            for (int t = 0; t < 8; ++t)
                #pragma unroll
                for (int r = 0; r < 4; ++r)
                    if (key0 + t * 16 + quad * 4 + r > qg) st[t][r] = -1e30f;
        }

        // ---- online softmax (exp2 domain), tree-reduced, defer-max ----
        float tm[8];
        #pragma unroll
        for (int t = 0; t < 8; ++t)
            tm[t] = fmaxf(fmaxf(st[t][0], st[t][1]), fmaxf(st[t][2], st[t][3]));
        float mx = fmaxf(fmaxf(fmaxf(tm[0], tm[1]), fmaxf(tm[2], tm[3])),
                         fmaxf(fmaxf(tm[4], tm[5]), fmaxf(tm[6], tm[7])));
        // common path: max grew by <= 8 for every lane -> keep old m,
        // skip cross-quad shfls and the whole rescale pass.
        if (!__all(mx <= m + 8.0f)) {
            float mf = fmaxf(mx, __shfl_xor(mx, 16, 64));
            mf = fmaxf(mf, __shfl_xor(mf, 32, 64));
            const float mnew  = fmaxf(m, mf);
            const float alpha = ex2(m - mnew);
            m = mnew;
            l *= alpha;
            #pragma unroll
            for (int t = 0; t < 4; ++t)
                #pragma unroll
                for (int r = 0; r < 4; ++r) oacc[t][r] *= alpha;
        }
        float p[8][4], ts[8];
        #pragma unroll
        for (int t = 0; t < 8; ++t) {
            p[t][0] = ex2(st[t][0] - m); p[t][1] = ex2(st[t][1] - m);
            p[t][2] = ex2(st[t][2] - m); p[t][3] = ex2(st[t][3] - m);
            ts[t] = (p[t][0] + p[t][1]) + (p[t][2] + p[t][3]);
        }
        l += ((ts[0] + ts[1]) + (ts[2] + ts[3])) +
             ((ts[4] + ts[5]) + (ts[6] + ts[7]));

        // write P^T rows: Ps[query=l16][key], packed pairs -> b64
        #pragma unroll
        for (int t = 0; t < 8; ++t) {
            uint2 w;
            w.x = pk_bf16(p[t][0], p[t][1]);
            w.y = pk_bf16(p[t][2], p[t][3]);
            *(uint2*)&Ps[wid][l16][t * 16 + quad * 4] = w;
        }

        // drain this wave's P ds_writes, read own P fragments (per-wave
        // scratch -> no barrier needed)
        asm volatile("s_waitcnt lgkmcnt(0)" ::: "memory");
        short8 pa[4];
        #pragma unroll
        for (int seg = 0; seg < 4; ++seg)
            pa[seg] = *(const short8*)&Ps[wid][l16][seg * 32 + quad * 8];

        // barrier B: V DMAs are the only VMEM in flight -> vmcnt(0) drains
        // them; s_barrier makes ALL waves' V rows visible. All waves are
        // past their Ks reads here (lgkm drained above), so Ks is free.
        asm volatile("s_waitcnt vmcnt(0)\n\ts_barrier" ::: "memory");

        // issue K chunk c+1 into Ks (WAR-safe after barrier B); in flight
        // across PV + loop-around, drained at the next barrier A.
        if (c + 1 < nch) {
            const ushort* kg = kbase + (size_t)(key0 + 128 + r0 + srow) * QKVN + sblk;
            async16(kg,                     &Ks[(r0     ) * 64]);
            async16(kg + (size_t) 8 * QKVN, &Ks[(r0 +  8) * 64]);
            async16(kg + (size_t)16 * QKVN, &Ks[(r0 + 16) * 64]);
            async16(kg + (size_t)24 * QKVN, &Ks[(r0 + 24) * 64]);
        }

        // ---- O^T += V^T @ P^T : V frags from LDS (swizzled rows) ----
        __builtin_amdgcn_s_setprio(1);
        #pragma unroll
        for (int t = 0; t < 4; ++t) {
            const int dr = t * 16 + l16;          // V d-row
            #pragma unroll
            for (int seg = 0; seg < 4; ++seg) {
                const int slot = ((seg * 4 + quad) ^ dr) & 15;
                short8 vv = *(const short8*)&Vs[dr * 128 + slot * 8];
                oacc[t] = __builtin_amdgcn_mfma_f32_16x16x32_bf16(vv, pa[seg], oacc[t], 0, 0, 0);
            }
        }
        __builtin_amdgcn_s_setprio(0);
    }

    // epilogue: cross-quad reduce the partial l, then y = O^T / l
    float lt = l + __shfl_xor(l, 16, 64);
    lt += __shfl_xor(lt, 32, 64);
    const float inv = 1.0f / lt;
    ushort* yrow = y + (size_t)(b * T_ + q0 + wid * 16 + l16) * (NH * HD) + h * HD;
    #pragma unroll
    for (int t = 0; t < 4; ++t) {
        ushort4 o;
        o.x = f2bf(oacc[t][0] * inv); o.y = f2bf(oacc[t][1] * inv);
        o.z = f2bf(oacc[t][2] * inv); o.w = f2bf(oacc[t][3] * inv);
        *(ushort4*)(yrow + t * 16 + quad * 4) = o;
    }
}

// ---------------- launcher ----------------
extern "C" void kernel_launch(void* const* d_in, const int* in_sizes, int n_in,
                              void* d_out, int out_size, void* d_ws, size_t ws_size,
                              hipStream_t stream)
{
    const float* x    = (const float*)d_in[0];
    const float* cosT = (const float*)d_in[1];
    const float* sinT = (const float*)d_in[2];
    const float* Wq   = (const float*)d_in[3];
    const float* Wk   = (const float*)d_in[4];
    const float* Wv   = (const float*)d_in[5];
    const float* Wo   = (const float*)d_in[6];
    float* out = (float*)d_out;

    const int M = B_ * T_;  // 4096
    ushort* xb     = (ushort*)d_ws;                       // 4096*1024
    ushort* qkv    = xb  + (size_t)M * C_;                // 4096*1536
    ushort* yb     = qkv + (size_t)M * QKVN;              // 4096*1024
    ushort* WqkvT  = yb  + (size_t)M * C_;                // 1536*1024
    ushort* WoT    = WqkvT + (size_t)QKVN * C_;           // 1024*1024
    ushort* vTbuf  = WoT + (size_t)C_ * C_;               // 2*256*2048

    dim3 blk(256);
    // converts + weight transposes, one launch
    prep<<<640 + (M * C_) / 1024, blk, 0, stream>>>(x, Wq, Wk, Wv, Wo, xb, WqkvT, WoT);
    // fused QKV projection: rope(+exp2 scale) epilogue, v written straight to vT
    gemm_bf16bt<true, true><<<dim3(QKVN / 64, M / 128), blk, 0, stream>>>(
        xb, WqkvT, qkv, vTbuf, cosT, sinT, M, QKVN, C_);
    // attention (XCD-swizzled, 1024 single-tile blocks heavy-first,
    // single-buffer K, 3 blocks/CU)
    attn_mfma<<<1024, blk, 0, stream>>>(qkv, vTbuf, yb);
    // output projection (fp32 out)
    gemm_bf16bt<false, false><<<dim3(C_ / 64, M / 128), blk, 0, stream>>>(
        yb, WoT, out, nullptr, nullptr, nullptr, M, C_, C_);
}